// Round 15
// baseline (758.914 us; speedup 1.0000x reference)
//
#include <hip/hip_runtime.h>
#include <hip/hip_bf16.h>
#include <stdint.h>

typedef unsigned int uint32;
typedef __attribute__((ext_vector_type(8))) short short8;   // 8 bf16 = 4 VGPRs
typedef __attribute__((ext_vector_type(4))) float float4v;  // MFMA C/D

#define FEAT 128
#define NGRAPH 64
#define GB   256     // binning blocks
#define NBK  512     // bucket slots (>= ceil(N/256))

// ---------- bf16 helpers ----------
__device__ __forceinline__ float bf2f_lo(uint32 v) {
    union { uint32 i; float f; } u; u.i = v << 16; return u.f;
}
__device__ __forceinline__ float bf2f_hi(uint32 v) {
    union { uint32 i; float f; } u; u.i = v & 0xffff0000u; return u.f;
}
__device__ __forceinline__ unsigned short f2bf(float f) {
    uint32 u = __builtin_bit_cast(uint32, f);
    uint32 r = (u + 0x7fffu + ((u >> 16) & 1u)) >> 16;      // RNE
    return (unsigned short)r;
}
__device__ __forceinline__ uint32 f2bf2(float lo, float hi) {
    return (uint32)f2bf(lo) | ((uint32)f2bf(hi) << 16);
}

// ================= preprocessing: atomic-free coarse counting sort =================
// bhistT TRANSPOSED: bhistT[bucket * GB + blk]. Block 0 also zero-inits pool/cntg.
__global__ void k_bhist(const int* __restrict__ dst, int* __restrict__ bhistT,
                        float* __restrict__ pool, int* __restrict__ cntg, int E) {
    __shared__ int h[NBK];
    int t = threadIdx.x, blk = blockIdx.x;
    if (blk == 0) {
        for (int i = t; i < NGRAPH * FEAT; i += 256) pool[i] = 0.f;
        if (t < NGRAPH) cntg[t] = 0;
    }
    for (int b = t; b < NBK; b += 256) h[b] = 0;
    __syncthreads();
    int chunk = (E + GB - 1) / GB;
    int lo = blk * chunk, hi = min(lo + chunk, E);
    for (int e = lo + t; e < hi; e += 256)
        atomicAdd(&h[dst[e] >> 8], 1);
    __syncthreads();
    for (int b = t; b < NBK; b += 256) bhistT[b * GB + blk] = h[b];
}

// one wave per bucket: shuffle-scan the 256 per-block counts in parallel.
__global__ void k_boffs_a(int* __restrict__ bhistT, int* __restrict__ btot) {
    int b = blockIdx.x, l = threadIdx.x;     // 64 threads
    int v[4];
    int base = b * GB + l * 4;
#pragma unroll
    for (int j = 0; j < 4; j++) v[j] = bhistT[base + j];
    int s = v[0] + v[1] + v[2] + v[3];
    int incl = s;
    for (int off = 1; off < 64; off <<= 1) {
        int u = __shfl_up(incl, off);
        if (l >= off) incl += u;
    }
    int excl = incl - s;
    int p0 = excl, p1 = p0 + v[0], p2 = p1 + v[1], p3 = p2 + v[2];
    bhistT[base + 0] = p0; bhistT[base + 1] = p1;
    bhistT[base + 2] = p2; bhistT[base + 3] = p3;
    if (l == 63) btot[b] = incl;
}

__global__ void k_boffs_b(const int* __restrict__ btot, int* __restrict__ bbase) {
    __shared__ int sc[NBK];
    int t = threadIdx.x;                     // 512 threads
    int s = btot[t];
    sc[t] = s;
    __syncthreads();
    for (int off = 1; off < NBK; off <<= 1) {
        int v = (t >= off) ? sc[t - off] : 0;
        __syncthreads();
        sc[t] += v;
        __syncthreads();
    }
    bbase[t] = sc[t] - s;
    if (t == NBK - 1) bbase[NBK] = sc[t];
}

__global__ void k_bscat(const int* __restrict__ src, const int* __restrict__ dst,
                        const int* __restrict__ bhistT, const int* __restrict__ bbase,
                        uint32* __restrict__ ebuf, int E) {
    __shared__ int cur[NBK];
    int t = threadIdx.x, blk = blockIdx.x;
    for (int b = t; b < NBK; b += 256) cur[b] = bbase[b] + bhistT[b * GB + blk];
    __syncthreads();
    int chunk = (E + GB - 1) / GB;
    int lo = blk * chunk, hi = min(lo + chunk, E);
    for (int e = lo + t; e < hi; e += 256) {
        int d = dst[e], s = src[e];
        int b = d >> 8;
        int p = atomicAdd(&cur[b], 1);       // LDS atomic
        ebuf[p] = ((uint32)s << 8) | (uint32)(d & 255);
    }
}

// fused: per-bucket histogram -> in-block scan -> rowp + dinv + CSR fill.
__global__ void k_csr(const uint32* __restrict__ ebuf, const int* __restrict__ bbase,
                      float* __restrict__ dinv, int* __restrict__ rowp,
                      int* __restrict__ csrc, int N, int E) {
    __shared__ int h[256];
    __shared__ int cur[256];
    int t = threadIdx.x, b = blockIdx.x;
    h[t] = 0;
    __syncthreads();
    int e0 = bbase[b], e1 = bbase[b + 1];
    for (int e = e0 + t; e < e1; e += 256)
        atomicAdd(&h[ebuf[e] & 255u], 1);
    __syncthreads();
    int deg = h[t];
    cur[t] = deg;
    __syncthreads();
    for (int off = 1; off < 256; off <<= 1) {
        int v = (t >= off) ? cur[t - off] : 0;
        __syncthreads();
        cur[t] += v;
        __syncthreads();
    }
    int r = bbase[b] + cur[t] - deg;         // exclusive
    int node = b * 256 + t;
    if (node < N) {
        rowp[node] = r;
        dinv[node] = rsqrtf((float)deg + 1.0f);  // deg = in-deg + self loop
    }
    if (b == 0 && t == 0) rowp[N] = E;
    cur[t] = r;
    __syncthreads();
    for (int e = e0 + t; e < e1; e += 256) {
        uint32 v = ebuf[e];
        int p = atomicAdd(&cur[v & 255u], 1);    // LDS atomic
        csrc[p] = (int)(v >> 8);
    }
}

// ---------- pre-swizzle W1/W2/W3 into MFMA fragment order, one launch ----------
__global__ void k_wswz3(const float* __restrict__ W1, const float* __restrict__ W2,
                        const float* __restrict__ W3, unsigned short* __restrict__ o1,
                        unsigned short* __restrict__ o2, unsigned short* __restrict__ o3) {
    int wid = blockIdx.x >> 3;               // 8 blocks per weight
    const float* W = (wid == 0) ? W1 : (wid == 1) ? W2 : W3;
    unsigned short* out = (wid == 0) ? o1 : (wid == 1) ? o2 : o3;
    int e = (blockIdx.x & 7) * 256 + threadIdx.x;  // 2048 entries
    int kt = e >> 9, ct = (e >> 6) & 7, lane = e & 63;
    int krow = kt * 32 + (lane >> 4) * 8;
    int col = ct * 16 + (lane & 15);
#pragma unroll
    for (int j = 0; j < 8; j++)
        out[e * 8 + j] = f2bf(W[(krow + j) * FEAT + col]);
}

// ---------- MFMA GEMM (transposed operands): Hb[row] = dinv[row] * (X[row] @ W) ----
// mfma(A=W^T-frag, B=X-frag): lane holds 4 consecutive feats of one node ->
// packed uint2 stores + 1 dinv/lane.
template <bool F32IN>
__global__ void k_gemm(const void* __restrict__ Xp,
                       const unsigned short* __restrict__ Wswz,
                       const float* __restrict__ dinv,
                       unsigned short* __restrict__ Hb, int N) {
    __shared__ unsigned short Wl[FEAT * FEAT];              // 32 KB
    {
        const uint4* Wg = (const uint4*)Wswz;
        uint4* Ws = (uint4*)Wl;
        for (int i = threadIdx.x; i < 2048; i += 256) Ws[i] = Wg[i];
    }
    __syncthreads();

    int wave = threadIdx.x >> 6, lane = threadIdx.x & 63;
    int r0 = (blockIdx.x * 4 + wave) * 16;
    if (r0 >= N) return;
    int m = lane & 15, q = lane >> 4;

    int arow = r0 + m; if (arow >= N) arow = N - 1;   // node index (B-operand n)
    short8 a[4];
    if (F32IN) {
        const float* Ar = (const float*)Xp + (long)arow * FEAT;
#pragma unroll
        for (int kt = 0; kt < 4; kt++) {
            float4 u = *(const float4*)(Ar + kt * 32 + q * 8);
            float4 v = *(const float4*)(Ar + kt * 32 + q * 8 + 4);
            short8 tv;
            tv[0] = (short)f2bf(u.x); tv[1] = (short)f2bf(u.y);
            tv[2] = (short)f2bf(u.z); tv[3] = (short)f2bf(u.w);
            tv[4] = (short)f2bf(v.x); tv[5] = (short)f2bf(v.y);
            tv[6] = (short)f2bf(v.z); tv[7] = (short)f2bf(v.w);
            a[kt] = tv;
        }
    } else {
        const short8* Ar = (const short8*)((const unsigned short*)Xp + (long)arow * FEAT);
#pragma unroll
        for (int kt = 0; kt < 4; kt++) a[kt] = Ar[kt * 4 + q];
    }

    const short8* Bl = (const short8*)Wl;
    float4v acc[8];
#pragma unroll
    for (int ct = 0; ct < 8; ct++) acc[ct] = (float4v){0.f, 0.f, 0.f, 0.f};
#pragma unroll
    for (int ct = 0; ct < 8; ct++) {
        acc[ct] = __builtin_amdgcn_mfma_f32_16x16x32_bf16(Bl[(0 * 8 + ct) * 64 + lane], a[0], acc[ct], 0, 0, 0);
        acc[ct] = __builtin_amdgcn_mfma_f32_16x16x32_bf16(Bl[(1 * 8 + ct) * 64 + lane], a[1], acc[ct], 0, 0, 0);
        acc[ct] = __builtin_amdgcn_mfma_f32_16x16x32_bf16(Bl[(2 * 8 + ct) * 64 + lane], a[2], acc[ct], 0, 0, 0);
        acc[ct] = __builtin_amdgcn_mfma_f32_16x16x32_bf16(Bl[(3 * 8 + ct) * 64 + lane], a[3], acc[ct], 0, 0, 0);
    }

    // D layout: node = r0 + (lane&15), feats = ct*16 + q*4 + reg  (4 consecutive)
    int node = r0 + m;
    bool ok = (node < N);
    float d = ok ? dinv[node] : 0.f;
#pragma unroll
    for (int ct = 0; ct < 8; ct++) {
        if (ok) {
            uint2 o;
            o.x = f2bf2(acc[ct][0] * d, acc[ct][1] * d);
            o.y = f2bf2(acc[ct][2] * d, acc[ct][3] * d);
            ((uint2*)(Hb + (long)node * FEAT + ct * 16))[q] = o;
        }
    }
}

// ---------- aggregation, feature-quarter split (XCD dedup experiment) ----------
// Hypothesis: blockIdx%8 -> XCD round-robin. Split each row into 4x 64B quarters;
// quarter q is processed only by blocks with (blockIdx%8)>>1 == q (a 2-XCD group),
// so each 64B line is fetched by ~2 L2s instead of ~7 of 8 -> row fetch 190->~51MB.
// Wave = 1 node x 1 quarter; 16 lanes (=64B line) per edge, 4 edges in flight,
// unroll x8 = 32 edges/iter; shfl_xor(16/32) reduce. Zero LDS (R10), no dev atomics (R12).
__global__ void k_agg(const uint32* __restrict__ Hb,
                      const int* __restrict__ rowp, const int* __restrict__ csrc,
                      const float* __restrict__ dinv, const float* __restrict__ bias,
                      uint32* __restrict__ OUTb, int N, int relu) {
    int wave = threadIdx.x >> 6, lane = threadIdx.x & 63;
    int slot = blockIdx.x & 7;
    int q = slot >> 1, s = slot & 1;
    int i = ((blockIdx.x >> 3) * 2 + s) * 4 + wave;  // node
    if (i >= N) return;
    int u = lane & 15, qi = lane >> 4;               // uint-in-quarter, edge-slot
    int qoff = q * 16;
    float a0 = 0.f, a1 = 0.f;
    int e0 = rowp[i], e1 = rowp[i + 1];
    int e = e0;
    for (; e + 32 <= e1; e += 32) {                  // 32 edges/iter (4 per slot x 8)
        int sx[8];
        uint32 h[8];
#pragma unroll
        for (int j = 0; j < 8; j++) sx[j] = csrc[e + 4 * j + qi];
#pragma unroll
        for (int j = 0; j < 8; j++) h[j] = Hb[(long)sx[j] * 64 + qoff + u];
#pragma unroll
        for (int j = 0; j < 8; j++) { a0 += bf2f_lo(h[j]); a1 += bf2f_hi(h[j]); }
    }
    {   // remainder (<32 edges), predicated — with avg deg 16 this is the main path
        int r = e1 - e;
        int sx[8];
        uint32 h[8];
#pragma unroll
        for (int j = 0; j < 8; j++) {
            int idx = 4 * j + qi;
            if (idx < r) sx[j] = csrc[e + idx];
        }
#pragma unroll
        for (int j = 0; j < 8; j++)
            if (4 * j + qi < r) h[j] = Hb[(long)sx[j] * 64 + qoff + u];
#pragma unroll
        for (int j = 0; j < 8; j++)
            if (4 * j + qi < r) { a0 += bf2f_lo(h[j]); a1 += bf2f_hi(h[j]); }
    }
    a0 += __shfl_xor(a0, 16); a1 += __shfl_xor(a1, 16);
    a0 += __shfl_xor(a0, 32); a1 += __shfl_xor(a1, 32);
    if (qi == 0) {
        uint32 hv = Hb[(long)i * 64 + qoff + u];     // self term (dinv-scaled)
        a0 += bf2f_lo(hv); a1 += bf2f_hi(hv);
        float di = dinv[i];
        float2 bb = ((const float2*)bias)[qoff + u];
        a0 = a0 * di + bb.x;
        a1 = a1 * di + bb.y;
        if (relu) { a0 = fmaxf(a0, 0.f); a1 = fmaxf(a1, 0.f); }
        OUTb[(long)i * 64 + qoff + u] = f2bf2(a0, a1);
    }
}

// ---------- pooling (batch sorted): run-length pre-reduce, shallow atomics ----------
__global__ void k_pool(const uint32* __restrict__ Gb, const int* __restrict__ batch,
                       float* __restrict__ pool, int* __restrict__ cntg, int N) {
    int t = threadIdx.x;                     // 64 threads: feat pair t
    int nb = gridDim.x;
    int chunk = (N + nb - 1) / nb;
    int lo = blockIdx.x * chunk, hi = min(lo + chunk, N);
    if (lo >= hi) return;
    float ax = 0.f, ay = 0.f;
    int cnt = 0;
    int cg = batch[lo];
    for (int i = lo; i < hi; i++) {
        int g = batch[i];
        if (g != cg) {
            atomicAdd(&pool[cg * FEAT + 2 * t], ax);
            atomicAdd(&pool[cg * FEAT + 2 * t + 1], ay);
            if (t == 0) atomicAdd(&cntg[cg], cnt);
            ax = ay = 0.f; cnt = 0; cg = g;
        }
        uint32 v = Gb[(long)i * 64 + t];
        ax += bf2f_lo(v); ay += bf2f_hi(v);
        cnt++;
    }
    atomicAdd(&pool[cg * FEAT + 2 * t], ax);
    atomicAdd(&pool[cg * FEAT + 2 * t + 1], ay);
    if (t == 0) atomicAdd(&cntg[cg], cnt);
}

// ---------- head ----------
__global__ void k_final(const float* __restrict__ pool, const int* __restrict__ cntg,
                        const float* __restrict__ Wlin, const float* __restrict__ blin,
                        float* __restrict__ out) {
    __shared__ float es[FEAT];
    int g = blockIdx.x, t = threadIdx.x;
    float c = (float)max(cntg[g], 1);
    float e = pool[g * FEAT + t] / c;
    es[t] = e;
    out[NGRAPH * 10 + g * FEAT + t] = e;
    __syncthreads();
    if (t < 10) {
        float a = blin[t];
        for (int k = 0; k < FEAT; k++)
            a += es[k] * Wlin[k * 10 + t];
        out[g * 10 + t] = a;
    }
}

// ---------------------------------------------------------------
extern "C" void kernel_launch(void* const* d_in, const int* in_sizes, int n_in,
                              void* d_out, int out_size, void* d_ws, size_t ws_size,
                              hipStream_t stream) {
    const float* x    = (const float*)d_in[0];
    const int*   ei   = (const int*)d_in[1];
    const int*   batch= (const int*)d_in[2];
    const float* W1   = (const float*)d_in[3];
    const float* b1   = (const float*)d_in[4];
    const float* W2   = (const float*)d_in[5];
    const float* b2   = (const float*)d_in[6];
    const float* W3   = (const float*)d_in[7];
    const float* b3   = (const float*)d_in[8];
    const float* Wlin = (const float*)d_in[9];
    const float* blin = (const float*)d_in[10];

    const int N = in_sizes[2];
    const int E = in_sizes[1] / 2;
    const int* src = ei;
    const int* dst = ei + E;
    const int NB = (N + 255) >> 8;           // coarse buckets used (<= NBK)

    // ---- workspace carve ----
    char* w = (char*)d_ws;
    auto take = [&](size_t bytes) {
        char* p = w;
        w += (bytes + 255) & ~(size_t)255;
        return p;
    };
    float*  dinv   = (float*) take((size_t)N * 4);
    int*    rowp   = (int*)   take((size_t)(N + 1) * 4);
    int*    csrc   = (int*)   take((size_t)E * 4);
    uint32* ebuf   = (uint32*)take((size_t)E * 4);
    int*    bhistT = (int*)   take((size_t)GB * NBK * 4);
    int*    btot   = (int*)   take((size_t)NBK * 4);
    int*    bbase  = (int*)   take((size_t)(NBK + 1) * 4);
    uint32* hbuf   = (uint32*)take((size_t)N * FEAT * 2);
    uint32* gbuf   = (uint32*)take((size_t)N * FEAT * 2);
    unsigned short* w1s = (unsigned short*)take(FEAT * FEAT * 2);
    unsigned short* w2s = (unsigned short*)take(FEAT * FEAT * 2);
    unsigned short* w3s = (unsigned short*)take(FEAT * FEAT * 2);
    float*  pool   = (float*) take((size_t)NGRAPH * FEAT * 4);
    int*    cntg   = (int*)   take((size_t)NGRAPH * 4);
    (void)ws_size; (void)n_in; (void)out_size;

    // --- atomic-free CSR build (pool/cntg zero-init folded into k_bhist) ---
    k_bhist  <<<GB, 256, 0, stream>>>(dst, bhistT, pool, cntg, E);
    k_boffs_a<<<NBK, 64, 0, stream>>>(bhistT, btot);
    k_boffs_b<<<1, NBK, 0, stream>>>(btot, bbase);
    k_bscat  <<<GB, 256, 0, stream>>>(src, dst, bhistT, bbase, ebuf, E);
    k_csr    <<<NB, 256, 0, stream>>>(ebuf, bbase, dinv, rowp, csrc, N, E);

    // weight swizzles (one launch for all 3)
    k_wswz3<<<24, 256, 0, stream>>>(W1, W2, W3, w1s, w2s, w3s);

    const int tile_blocks = (N + 63) / 64;
    const int agg_blocks  = ((N + 7) / 8) * 8;   // 8 slots x ceil(N/8) node coverage

    // layer 1
    k_gemm<true> <<<tile_blocks, 256, 0, stream>>>(x, w1s, dinv, (unsigned short*)hbuf, N);
    k_agg<<<agg_blocks, 256, 0, stream>>>(hbuf, rowp, csrc, dinv, b1, gbuf, N, 1);
    // layer 2
    k_gemm<false><<<tile_blocks, 256, 0, stream>>>(gbuf, w2s, dinv, (unsigned short*)hbuf, N);
    k_agg<<<agg_blocks, 256, 0, stream>>>(hbuf, rowp, csrc, dinv, b2, gbuf, N, 1);
    // layer 3
    k_gemm<false><<<tile_blocks, 256, 0, stream>>>(gbuf, w3s, dinv, (unsigned short*)hbuf, N);
    k_agg<<<agg_blocks, 256, 0, stream>>>(hbuf, rowp, csrc, dinv, b3, gbuf, N, 0);

    // pooling + head
    k_pool <<<4096, 64, 0, stream>>>(gbuf, batch, pool, cntg, N);
    k_final<<<NGRAPH, 128, 0, stream>>>(pool, cntg, Wlin, blin, (float*)d_out);
}

// Round 16
// 427.109 us; speedup vs baseline: 1.7769x; 1.7769x over previous
//
#include <hip/hip_runtime.h>
#include <hip/hip_bf16.h>
#include <stdint.h>

typedef unsigned int uint32;
typedef __attribute__((ext_vector_type(8))) short short8;   // 8 bf16 = 4 VGPRs
typedef __attribute__((ext_vector_type(4))) float float4v;  // MFMA C/D

#define FEAT 128
#define NGRAPH 64
#define GB   256     // binning blocks
#define NBK  512     // bucket slots (>= ceil(N/256))

// ---------- bf16 helpers ----------
__device__ __forceinline__ float bf2f_lo(uint32 v) {
    union { uint32 i; float f; } u; u.i = v << 16; return u.f;
}
__device__ __forceinline__ float bf2f_hi(uint32 v) {
    union { uint32 i; float f; } u; u.i = v & 0xffff0000u; return u.f;
}
__device__ __forceinline__ unsigned short f2bf(float f) {
    uint32 u = __builtin_bit_cast(uint32, f);
    uint32 r = (u + 0x7fffu + ((u >> 16) & 1u)) >> 16;      // RNE
    return (unsigned short)r;
}
__device__ __forceinline__ uint32 f2bf2(float lo, float hi) {
    return (uint32)f2bf(lo) | ((uint32)f2bf(hi) << 16);
}

// ================= preprocessing: atomic-free coarse counting sort =================
// bhistT TRANSPOSED: bhistT[bucket * GB + blk]. Block 0 also zero-inits pool/cntg.
// Blocks >= GB do the W1/W2/W3 swizzle (independent work; saves one dispatch).
__global__ void k_bhist(const int* __restrict__ dst, int* __restrict__ bhistT,
                        float* __restrict__ pool, int* __restrict__ cntg,
                        const float* __restrict__ W1, const float* __restrict__ W2,
                        const float* __restrict__ W3, unsigned short* __restrict__ o1,
                        unsigned short* __restrict__ o2, unsigned short* __restrict__ o3,
                        int E) {
    int t = threadIdx.x, blk = blockIdx.x;
    if (blk >= GB) {                         // ---- weight swizzle branch ----
        int b2 = blk - GB;                   // 0..23: 8 blocks per weight
        int wid = b2 >> 3;
        const float* W = (wid == 0) ? W1 : (wid == 1) ? W2 : W3;
        unsigned short* out = (wid == 0) ? o1 : (wid == 1) ? o2 : o3;
        int e = (b2 & 7) * 256 + t;          // 2048 entries
        int kt = e >> 9, ct = (e >> 6) & 7, lane = e & 63;
        int krow = kt * 32 + (lane >> 4) * 8;
        int col = ct * 16 + (lane & 15);
#pragma unroll
        for (int j = 0; j < 8; j++)
            out[e * 8 + j] = f2bf(W[(krow + j) * FEAT + col]);
        return;
    }
    __shared__ int h[NBK];
    if (blk == 0) {
        for (int i = t; i < NGRAPH * FEAT; i += 256) pool[i] = 0.f;
        if (t < NGRAPH) cntg[t] = 0;
    }
    for (int b = t; b < NBK; b += 256) h[b] = 0;
    __syncthreads();
    int chunk = (E + GB - 1) / GB;
    int lo = blk * chunk, hi = min(lo + chunk, E);
    for (int e = lo + t; e < hi; e += 256)
        atomicAdd(&h[dst[e] >> 8], 1);
    __syncthreads();
    for (int b = t; b < NBK; b += 256) bhistT[b * GB + blk] = h[b];
}

// one wave per bucket: shuffle-scan the 256 per-block counts in parallel.
__global__ void k_boffs_a(int* __restrict__ bhistT, int* __restrict__ btot) {
    int b = blockIdx.x, l = threadIdx.x;     // 64 threads
    int v[4];
    int base = b * GB + l * 4;
#pragma unroll
    for (int j = 0; j < 4; j++) v[j] = bhistT[base + j];
    int s = v[0] + v[1] + v[2] + v[3];
    int incl = s;
    for (int off = 1; off < 64; off <<= 1) {
        int u = __shfl_up(incl, off);
        if (l >= off) incl += u;
    }
    int excl = incl - s;
    int p0 = excl, p1 = p0 + v[0], p2 = p1 + v[1], p3 = p2 + v[2];
    bhistT[base + 0] = p0; bhistT[base + 1] = p1;
    bhistT[base + 2] = p2; bhistT[base + 3] = p3;
    if (l == 63) btot[b] = incl;
}

__global__ void k_boffs_b(const int* __restrict__ btot, int* __restrict__ bbase) {
    __shared__ int sc[NBK];
    int t = threadIdx.x;                     // 512 threads
    int s = btot[t];
    sc[t] = s;
    __syncthreads();
    for (int off = 1; off < NBK; off <<= 1) {
        int v = (t >= off) ? sc[t - off] : 0;
        __syncthreads();
        sc[t] += v;
        __syncthreads();
    }
    bbase[t] = sc[t] - s;
    if (t == NBK - 1) bbase[NBK] = sc[t];
}

__global__ void k_bscat(const int* __restrict__ src, const int* __restrict__ dst,
                        const int* __restrict__ bhistT, const int* __restrict__ bbase,
                        uint32* __restrict__ ebuf, int E) {
    __shared__ int cur[NBK];
    int t = threadIdx.x, blk = blockIdx.x;
    for (int b = t; b < NBK; b += 256) cur[b] = bbase[b] + bhistT[b * GB + blk];
    __syncthreads();
    int chunk = (E + GB - 1) / GB;
    int lo = blk * chunk, hi = min(lo + chunk, E);
    for (int e = lo + t; e < hi; e += 256) {
        int d = dst[e], s = src[e];
        int b = d >> 8;
        int p = atomicAdd(&cur[b], 1);       // LDS atomic
        ebuf[p] = ((uint32)s << 8) | (uint32)(d & 255);
    }
}

// fused: per-bucket histogram -> in-block scan -> rowp + dinv + CSR fill.
__global__ void k_csr(const uint32* __restrict__ ebuf, const int* __restrict__ bbase,
                      float* __restrict__ dinv, int* __restrict__ rowp,
                      int* __restrict__ csrc, int N, int E) {
    __shared__ int h[256];
    __shared__ int cur[256];
    int t = threadIdx.x, b = blockIdx.x;
    h[t] = 0;
    __syncthreads();
    int e0 = bbase[b], e1 = bbase[b + 1];
    for (int e = e0 + t; e < e1; e += 256)
        atomicAdd(&h[ebuf[e] & 255u], 1);
    __syncthreads();
    int deg = h[t];
    cur[t] = deg;
    __syncthreads();
    for (int off = 1; off < 256; off <<= 1) {
        int v = (t >= off) ? cur[t - off] : 0;
        __syncthreads();
        cur[t] += v;
        __syncthreads();
    }
    int r = bbase[b] + cur[t] - deg;         // exclusive
    int node = b * 256 + t;
    if (node < N) {
        rowp[node] = r;
        dinv[node] = rsqrtf((float)deg + 1.0f);  // deg = in-deg + self loop
    }
    if (b == 0 && t == 0) rowp[N] = E;
    cur[t] = r;
    __syncthreads();
    for (int e = e0 + t; e < e1; e += 256) {
        uint32 v = ebuf[e];
        int p = atomicAdd(&cur[v & 255u], 1);    // LDS atomic
        csrc[p] = (int)(v >> 8);
    }
}

// ---------- MFMA GEMM (transposed operands): Hb[row] = dinv[row] * (X[row] @ W) ----
// mfma(A=W^T-frag, B=X-frag): lane holds 4 consecutive feats of one node ->
// packed uint2 stores + 1 dinv/lane.
template <bool F32IN>
__global__ void k_gemm(const void* __restrict__ Xp,
                       const unsigned short* __restrict__ Wswz,
                       const float* __restrict__ dinv,
                       unsigned short* __restrict__ Hb, int N) {
    __shared__ unsigned short Wl[FEAT * FEAT];              // 32 KB
    {
        const uint4* Wg = (const uint4*)Wswz;
        uint4* Ws = (uint4*)Wl;
        for (int i = threadIdx.x; i < 2048; i += 256) Ws[i] = Wg[i];
    }
    __syncthreads();

    int wave = threadIdx.x >> 6, lane = threadIdx.x & 63;
    int r0 = (blockIdx.x * 4 + wave) * 16;
    if (r0 >= N) return;
    int m = lane & 15, q = lane >> 4;

    int arow = r0 + m; if (arow >= N) arow = N - 1;   // node index (B-operand n)
    short8 a[4];
    if (F32IN) {
        const float* Ar = (const float*)Xp + (long)arow * FEAT;
#pragma unroll
        for (int kt = 0; kt < 4; kt++) {
            float4 u = *(const float4*)(Ar + kt * 32 + q * 8);
            float4 v = *(const float4*)(Ar + kt * 32 + q * 8 + 4);
            short8 tv;
            tv[0] = (short)f2bf(u.x); tv[1] = (short)f2bf(u.y);
            tv[2] = (short)f2bf(u.z); tv[3] = (short)f2bf(u.w);
            tv[4] = (short)f2bf(v.x); tv[5] = (short)f2bf(v.y);
            tv[6] = (short)f2bf(v.z); tv[7] = (short)f2bf(v.w);
            a[kt] = tv;
        }
    } else {
        const short8* Ar = (const short8*)((const unsigned short*)Xp + (long)arow * FEAT);
#pragma unroll
        for (int kt = 0; kt < 4; kt++) a[kt] = Ar[kt * 4 + q];
    }

    const short8* Bl = (const short8*)Wl;
    float4v acc[8];
#pragma unroll
    for (int ct = 0; ct < 8; ct++) acc[ct] = (float4v){0.f, 0.f, 0.f, 0.f};
#pragma unroll
    for (int ct = 0; ct < 8; ct++) {
        acc[ct] = __builtin_amdgcn_mfma_f32_16x16x32_bf16(Bl[(0 * 8 + ct) * 64 + lane], a[0], acc[ct], 0, 0, 0);
        acc[ct] = __builtin_amdgcn_mfma_f32_16x16x32_bf16(Bl[(1 * 8 + ct) * 64 + lane], a[1], acc[ct], 0, 0, 0);
        acc[ct] = __builtin_amdgcn_mfma_f32_16x16x32_bf16(Bl[(2 * 8 + ct) * 64 + lane], a[2], acc[ct], 0, 0, 0);
        acc[ct] = __builtin_amdgcn_mfma_f32_16x16x32_bf16(Bl[(3 * 8 + ct) * 64 + lane], a[3], acc[ct], 0, 0, 0);
    }

    // D layout: node = r0 + (lane&15), feats = ct*16 + q*4 + reg  (4 consecutive)
    int node = r0 + m;
    bool ok = (node < N);
    float d = ok ? dinv[node] : 0.f;
#pragma unroll
    for (int ct = 0; ct < 8; ct++) {
        if (ok) {
            uint2 o;
            o.x = f2bf2(acc[ct][0] * d, acc[ct][1] * d);
            o.y = f2bf2(acc[ct][2] * d, acc[ct][3] * d);
            ((uint2*)(Hb + (long)node * FEAT + ct * 16))[q] = o;
        }
    }
}

// ---------- aggregation: OUT[i] = dinv_i * (sum_e Hb'[src_e] + Hb'[i]) + b ----------
// Half-wave, FULL-row (256B) gathers — R15 lesson: never shrink random gathers
// below 128B sector granularity, and XCD RR block mapping is not exploitable.
// Zero LDS / full occupancy (R10); no device-atomic epilogue (R12).
__global__ void k_agg(const uint32* __restrict__ Hb,
                      const int* __restrict__ rowp, const int* __restrict__ csrc,
                      const float* __restrict__ dinv, const float* __restrict__ bias,
                      uint32* __restrict__ OUTb, int N, int relu) {
    int wave = threadIdx.x >> 6, lane = threadIdx.x & 63;
    int i = blockIdx.x * 4 + wave;
    if (i >= N) return;
    int f = lane & 31, half = lane >> 5;
    const uint2* H2 = (const uint2*)Hb;
    float a0 = 0.f, a1 = 0.f, a2 = 0.f, a3 = 0.f;
    int e0 = rowp[i], e1 = rowp[i + 1];
    int e = e0;
    for (; e + 16 <= e1; e += 16) {          // 16 edges/iter (8 per half)
        int  s[8];
        uint2 h[8];
#pragma unroll
        for (int j = 0; j < 8; j++) s[j] = csrc[e + 2 * j + half];
#pragma unroll
        for (int j = 0; j < 8; j++) h[j] = H2[(long)s[j] * 32 + f];
#pragma unroll
        for (int j = 0; j < 8; j++) {
            a0 += bf2f_lo(h[j].x); a1 += bf2f_hi(h[j].x);
            a2 += bf2f_lo(h[j].y); a3 += bf2f_hi(h[j].y);
        }
    }
    {   // remainder (<16 edges), predicated
        int r = e1 - e;
        int  s[8];
        uint2 h[8];
#pragma unroll
        for (int j = 0; j < 8; j++) {
            int idx = 2 * j + half;
            if (idx < r) s[j] = csrc[e + idx];
        }
#pragma unroll
        for (int j = 0; j < 8; j++)
            if (2 * j + half < r) h[j] = H2[(long)s[j] * 32 + f];
#pragma unroll
        for (int j = 0; j < 8; j++)
            if (2 * j + half < r) {
                a0 += bf2f_lo(h[j].x); a1 += bf2f_hi(h[j].x);
                a2 += bf2f_lo(h[j].y); a3 += bf2f_hi(h[j].y);
            }
    }
    a0 += __shfl_xor(a0, 32);
    a1 += __shfl_xor(a1, 32);
    a2 += __shfl_xor(a2, 32);
    a3 += __shfl_xor(a3, 32);
    if (half == 0) {
        uint2 hv = H2[(long)i * 32 + f];     // self term (already dinv-scaled)
        a0 += bf2f_lo(hv.x); a1 += bf2f_hi(hv.x);
        a2 += bf2f_lo(hv.y); a3 += bf2f_hi(hv.y);
        float di = dinv[i];
        float4 bb = ((const float4*)bias)[f];
        a0 = a0 * di + bb.x; a1 = a1 * di + bb.y;
        a2 = a2 * di + bb.z; a3 = a3 * di + bb.w;
        if (relu) {
            a0 = fmaxf(a0, 0.f); a1 = fmaxf(a1, 0.f);
            a2 = fmaxf(a2, 0.f); a3 = fmaxf(a3, 0.f);
        }
        uint2 o;
        o.x = f2bf2(a0, a1);
        o.y = f2bf2(a2, a3);
        ((uint2*)OUTb)[(long)i * 32 + f] = o;
    }
}

// ---------- pooling (batch sorted): run-length pre-reduce, shallow atomics ----------
__global__ void k_pool(const uint32* __restrict__ Gb, const int* __restrict__ batch,
                       float* __restrict__ pool, int* __restrict__ cntg, int N) {
    int t = threadIdx.x;                     // 64 threads: feat pair t
    int nb = gridDim.x;
    int chunk = (N + nb - 1) / nb;
    int lo = blockIdx.x * chunk, hi = min(lo + chunk, N);
    if (lo >= hi) return;
    float ax = 0.f, ay = 0.f;
    int cnt = 0;
    int cg = batch[lo];
    for (int i = lo; i < hi; i++) {
        int g = batch[i];
        if (g != cg) {
            atomicAdd(&pool[cg * FEAT + 2 * t], ax);
            atomicAdd(&pool[cg * FEAT + 2 * t + 1], ay);
            if (t == 0) atomicAdd(&cntg[cg], cnt);
            ax = ay = 0.f; cnt = 0; cg = g;
        }
        uint32 v = Gb[(long)i * 64 + t];
        ax += bf2f_lo(v); ay += bf2f_hi(v);
        cnt++;
    }
    atomicAdd(&pool[cg * FEAT + 2 * t], ax);
    atomicAdd(&pool[cg * FEAT + 2 * t + 1], ay);
    if (t == 0) atomicAdd(&cntg[cg], cnt);
}

// ---------- head ----------
__global__ void k_final(const float* __restrict__ pool, const int* __restrict__ cntg,
                        const float* __restrict__ Wlin, const float* __restrict__ blin,
                        float* __restrict__ out) {
    __shared__ float es[FEAT];
    int g = blockIdx.x, t = threadIdx.x;
    float c = (float)max(cntg[g], 1);
    float e = pool[g * FEAT + t] / c;
    es[t] = e;
    out[NGRAPH * 10 + g * FEAT + t] = e;
    __syncthreads();
    if (t < 10) {
        float a = blin[t];
        for (int k = 0; k < FEAT; k++)
            a += es[k] * Wlin[k * 10 + t];
        out[g * 10 + t] = a;
    }
}

// ---------------------------------------------------------------
extern "C" void kernel_launch(void* const* d_in, const int* in_sizes, int n_in,
                              void* d_out, int out_size, void* d_ws, size_t ws_size,
                              hipStream_t stream) {
    const float* x    = (const float*)d_in[0];
    const int*   ei   = (const int*)d_in[1];
    const int*   batch= (const int*)d_in[2];
    const float* W1   = (const float*)d_in[3];
    const float* b1   = (const float*)d_in[4];
    const float* W2   = (const float*)d_in[5];
    const float* b2   = (const float*)d_in[6];
    const float* W3   = (const float*)d_in[7];
    const float* b3   = (const float*)d_in[8];
    const float* Wlin = (const float*)d_in[9];
    const float* blin = (const float*)d_in[10];

    const int N = in_sizes[2];
    const int E = in_sizes[1] / 2;
    const int* src = ei;
    const int* dst = ei + E;
    const int NB = (N + 255) >> 8;           // coarse buckets used (<= NBK)

    // ---- workspace carve ----
    char* w = (char*)d_ws;
    auto take = [&](size_t bytes) {
        char* p = w;
        w += (bytes + 255) & ~(size_t)255;
        return p;
    };
    float*  dinv   = (float*) take((size_t)N * 4);
    int*    rowp   = (int*)   take((size_t)(N + 1) * 4);
    int*    csrc   = (int*)   take((size_t)E * 4);
    uint32* ebuf   = (uint32*)take((size_t)E * 4);
    int*    bhistT = (int*)   take((size_t)GB * NBK * 4);
    int*    btot   = (int*)   take((size_t)NBK * 4);
    int*    bbase  = (int*)   take((size_t)(NBK + 1) * 4);
    uint32* hbuf   = (uint32*)take((size_t)N * FEAT * 2);
    uint32* gbuf   = (uint32*)take((size_t)N * FEAT * 2);
    unsigned short* w1s = (unsigned short*)take(FEAT * FEAT * 2);
    unsigned short* w2s = (unsigned short*)take(FEAT * FEAT * 2);
    unsigned short* w3s = (unsigned short*)take(FEAT * FEAT * 2);
    float*  pool   = (float*) take((size_t)NGRAPH * FEAT * 4);
    int*    cntg   = (int*)   take((size_t)NGRAPH * 4);
    (void)ws_size; (void)n_in; (void)out_size;

    // --- atomic-free CSR build (pool/cntg zero-init + W swizzle folded into k_bhist) ---
    k_bhist  <<<GB + 24, 256, 0, stream>>>(dst, bhistT, pool, cntg,
                                           W1, W2, W3, w1s, w2s, w3s, E);
    k_boffs_a<<<NBK, 64, 0, stream>>>(bhistT, btot);
    k_boffs_b<<<1, NBK, 0, stream>>>(btot, bbase);
    k_bscat  <<<GB, 256, 0, stream>>>(src, dst, bhistT, bbase, ebuf, E);
    k_csr    <<<NB, 256, 0, stream>>>(ebuf, bbase, dinv, rowp, csrc, N, E);

    const int tile_blocks = (N + 63) / 64;
    const int agg_blocks  = (N + 3) / 4;

    // layer 1
    k_gemm<true> <<<tile_blocks, 256, 0, stream>>>(x, w1s, dinv, (unsigned short*)hbuf, N);
    k_agg<<<agg_blocks, 256, 0, stream>>>(hbuf, rowp, csrc, dinv, b1, gbuf, N, 1);
    // layer 2
    k_gemm<false><<<tile_blocks, 256, 0, stream>>>(gbuf, w2s, dinv, (unsigned short*)hbuf, N);
    k_agg<<<agg_blocks, 256, 0, stream>>>(hbuf, rowp, csrc, dinv, b2, gbuf, N, 1);
    // layer 3
    k_gemm<false><<<tile_blocks, 256, 0, stream>>>(gbuf, w3s, dinv, (unsigned short*)hbuf, N);
    k_agg<<<agg_blocks, 256, 0, stream>>>(hbuf, rowp, csrc, dinv, b3, gbuf, N, 0);

    // pooling + head
    k_pool <<<4096, 64, 0, stream>>>(gbuf, batch, pool, cntg, N);
    k_final<<<NGRAPH, 128, 0, stream>>>(pool, cntg, Wlin, blin, (float*)d_out);
}